// Round 1
// 645.302 us; speedup vs baseline: 1.1750x; 1.1750x over previous
//
#include <hip/hip_runtime.h>
#include <hip/hip_fp16.h>

#define NT 25
#define NXY 448
#define NPIX (448*448)
#define PXY 115
#define SXY 111

#define TW 32
#define TH 8

typedef float vf2 __attribute__((ext_vector_type(2)));

// complex MAC via packed fp32: z += x * w  (z,x,w are (re,im) pairs)
//  pk1: z.lo += x.lo*w.lo ; z.hi += x.lo*w.hi      (xr*wr, xr*wi)
//  pk2: z.lo += -x.hi*w.hi ; z.hi += x.hi*w.lo     (-xi*wi, xi*wr)
// weight operand comes from an SGPR pair (wave-uniform) -> zero DS/VALU cost to source it
#define CMACS(z, x, w)                                                                             \
    asm("v_pk_fma_f32 %0, %1, %2, %0 op_sel:[0,0,0] op_sel_hi:[0,1,1]"                             \
        : "+v"(z) : "v"(x), "s"(w));                                                               \
    asm("v_pk_fma_f32 %0, %1, %2, %0 op_sel:[1,1,0] op_sel_hi:[1,0,1] neg_lo:[0,1,0]"              \
        : "+v"(z) : "v"(x), "s"(w));

// ---------------- K0: transpose weights into (tap-major, channel-contiguous) vf2 layout
// wt1[tap*12 + c]       = (w1r[c*25+tap],        w1i[c*25+tap])
// wt2[(c1*3+dt)*12 + c2]= (w2r[(c2*12+c1)*3+dt], w2i[(c2*12+c1)*3+dt])
__global__ void k_prep(const float* __restrict__ w1r, const float* __restrict__ w1i,
                       const float* __restrict__ w2r, const float* __restrict__ w2i,
                       float* __restrict__ wt1, float* __restrict__ wt2)
{
    int i = blockIdx.x * 256 + threadIdx.x;
    if (i < 300) {
        int c = i / 25, tap = i - c * 25;
        wt1[(tap*12 + c)*2]     = w1r[i];
        wt1[(tap*12 + c)*2 + 1] = w1i[i];
    }
    if (i < 432) {
        int dt = i % 3; int t = i / 3; int c1 = t % 12; int c2 = t / 12;
        wt2[((c1*3+dt)*12 + c2)*2]     = w2r[i];
        wt2[((c1*3+dt)*12 + c2)*2 + 1] = w2i[i];
    }
}

// ---------------- K1: fused complex conv1(1->12,5x5)+ReLU -> conv2(12->12,3 temporal)+ReLU
// -> conv3(12->1) real part ; out = (x_re - denR*tsc)*pwv   (fp32, [25,448,448])
// Weights come in via SCALAR loads (uniform addresses -> s_load, K$-resident) and feed
// v_pk_fma_f32 as SGPR-pair operands. LDS holds only the double-buffered input tile.
__global__ __launch_bounds__(256, 4) void k_conv(
    const float* __restrict__ re, const float* __restrict__ im,
    const vf2* __restrict__ wt1, const vf2* __restrict__ wt2,
    const float* __restrict__ b1r, const float* __restrict__ b1i,
    const float* __restrict__ b2r, const float* __restrict__ b2i,
    const float* __restrict__ w3r, const float* __restrict__ w3i,
    const float* __restrict__ b3r,
    const float* __restrict__ tau_w, const float* __restrict__ p_w,
    const int* __restrict__ num_iter,
    float* __restrict__ out)
{
    __shared__ vf2 s_b1v[12], s_b2v[12];
    __shared__ float s_w3r[12], s_w3i[12], s_b3[1];
    __shared__ vf2 s_inv[2][12*36];       // double-buffered input tile (re,im), 2-halo

    const int tid = threadIdx.x;
    const int tx = tid & 31;
    const int ty = tid >> 5;
    const int Y0 = blockIdx.x * TW;
    const int X0 = blockIdx.y * TH;

    if (tid < 12) {
        s_b1v[tid] = (vf2){b1r[tid], b1i[tid]};
        s_b2v[tid] = (vf2){b2r[tid], b2i[tid]};
        s_w3r[tid] = w3r[tid]; s_w3i[tid] = w3i[tid];
    }
    if (tid == 0) s_b3[0] = b3r[0];

    const float tsc = fmaxf(tau_w[0], 0.f) / (float)num_iter[0];
    const float pwv = fmaxf(p_w[0], 0.f);

    // persistent h1 slots: hA = frame tc-1, hB = frame tc, hC = frame tc+1 (relu'd, fp16 pairs)
    __half2 hA[12], hB[12], hC[12];
    #pragma unroll
    for (int c = 0; c < 12; ++c) { hA[c] = __half2{}; hB[c] = __half2{}; hC[c] = __half2{}; }

    // stage frame tf into buffer tf&1
    auto stage = [&](int tf) {
        const float* rp = re + (size_t)tf * NPIX;
        const float* ip = im + (size_t)tf * NPIX;
        vf2* dst = s_inv[tf & 1];
        for (int idx = tid; idx < 12*36; idx += 256) {
            int r = idx / 36, c = idx - r*36;
            int gx = X0 + r - 2, gy = Y0 + c - 2;
            bool ok = (gx >= 0) && (gx < NXY) && (gy >= 0) && (gy < NXY);
            int cgx = ok ? gx : 0, cgy = ok ? gy : 0;
            size_t a = (size_t)cgx * NXY + cgy;
            float vr = rp[a], vi = ip[a];
            dst[idx] = (vf2){ok ? vr : 0.f, ok ? vi : 0.f};
        }
    };

    // conv1 for frame tf -> relu -> fp16-pack into hs (register array, static indexing)
    auto conv1_to = [&](int tf, __half2 (&hs)[12]) {
        vf2 a[12];
        #pragma unroll
        for (int c = 0; c < 12; ++c) a[c] = s_b1v[c];
        const vf2* sin_ = s_inv[tf & 1];
        #pragma unroll 1
        for (int ky = 0; ky < 5; ++ky) {
            const vf2* irow = &sin_[(ty+ky)*36 + tx];
            const vf2* wrow = &wt1[ky*5*12];
            #pragma unroll
            for (int kx = 0; kx < 5; ++kx) {
                vf2 x = irow[kx];
                const vf2* wp = wrow + kx*12;
                #pragma unroll
                for (int c = 0; c < 12; ++c) { vf2 w = wp[c]; CMACS(a[c], x, w); }
            }
        }
        #pragma unroll
        for (int c = 0; c < 12; ++c)
            hs[c] = __floats2half2_rn(fmaxf(a[c].x,0.f), fmaxf(a[c].y,0.f));
    };

    // conv2(+ReLU)+conv3+epilogue for output frame tc; h slots passed by reference (static)
    auto do_out = [&](int tc, __half2 (&hp)[12], __half2 (&hc)[12], __half2 (&hn)[12],
                      bool hasP, bool hasN) {
        vf2 z[12];
        #pragma unroll
        for (int c = 0; c < 12; ++c) z[c] = s_b2v[c];
        if (hasP) {
            #pragma unroll
            for (int c1 = 0; c1 < 12; ++c1) {
                vf2 x = (vf2){__low2float(hp[c1]), __high2float(hp[c1])};
                const vf2* wp = &wt2[(c1*3+0)*12];
                #pragma unroll
                for (int c2 = 0; c2 < 12; ++c2) { vf2 w = wp[c2]; CMACS(z[c2], x, w); }
            }
        }
        {
            #pragma unroll
            for (int c1 = 0; c1 < 12; ++c1) {
                vf2 x = (vf2){__low2float(hc[c1]), __high2float(hc[c1])};
                const vf2* wp = &wt2[(c1*3+1)*12];
                #pragma unroll
                for (int c2 = 0; c2 < 12; ++c2) { vf2 w = wp[c2]; CMACS(z[c2], x, w); }
            }
        }
        if (hasN) {
            #pragma unroll
            for (int c1 = 0; c1 < 12; ++c1) {
                vf2 x = (vf2){__low2float(hn[c1]), __high2float(hn[c1])};
                const vf2* wp = &wt2[(c1*3+2)*12];
                #pragma unroll
                for (int c2 = 0; c2 < 12; ++c2) { vf2 w = wp[c2]; CMACS(z[c2], x, w); }
            }
        }
        float dR = s_b3[0];
        #pragma unroll
        for (int c = 0; c < 12; ++c)
            dR += fmaxf(z[c].x,0.f)*s_w3r[c] - fmaxf(z[c].y,0.f)*s_w3i[c];
        size_t idx = (size_t)tc*NPIX + (size_t)(X0+ty)*NXY + (Y0+tx);
        out[idx] = (re[idx] - dR * tsc) * pwv;
    };

    // frame 0
    stage(0);
    __syncthreads();
    conv1_to(0, hB);

    #pragma unroll 1
    for (int tf = 1; tf < NT; ++tf) {
        stage(tf);                 // writes buf tf&1; other waves read buf (tf-1)&1 only
        __syncthreads();
        conv1_to(tf, hC);
        do_out(tf - 1, hA, hB, hC, (tf - 1) >= 1, true);
        #pragma unroll
        for (int c = 0; c < 12; ++c) { hA[c] = hB[c]; hB[c] = hC[c]; }
    }
    // final frame tc = 24: hA=h[23], hB=h[24]
    do_out(NT - 1, hA, hB, hC, true, false);
}

// ---------------- K2: Gram matrices G_b = M_b M_b^H  (80 x 5x5 complex Hermitian)
__global__ __launch_bounds__(256) void k_gram(
    const float* __restrict__ re, const float* __restrict__ im,
    float* __restrict__ gG)
{
    const int b = blockIdx.x;            // 0..79  = chunk*16 + i*4 + j
    const int chunk = b >> 4;
    const int pidx = b & 15;
    const int X0 = (pidx >> 2) * SXY;
    const int Y0 = (pidx & 3) * SXY;
    const int tid = threadIdx.x;

    float acc[50];
    #pragma unroll
    for (int k = 0; k < 50; ++k) acc[k] = 0.f;

    const int npx = PXY * PXY;           // 13225
    for (int pi = tid; pi < npx; pi += 256) {
        int px = pi / PXY, py = pi % PXY;
        size_t base = (size_t)(X0 + px) * NXY + (Y0 + py);
        float xr[5], xi[5];
        #pragma unroll
        for (int r = 0; r < 5; ++r) {
            size_t a = (size_t)(chunk*5 + r) * NPIX + base;
            xr[r] = re[a]; xi[r] = im[a];
        }
        #pragma unroll
        for (int t1 = 0; t1 < 5; ++t1)
            #pragma unroll
            for (int t2 = 0; t2 < 5; ++t2) {
                acc[(t1*5+t2)*2]   += xr[t1]*xr[t2] + xi[t1]*xi[t2];
                acc[(t1*5+t2)*2+1] += xi[t1]*xr[t2] - xr[t1]*xi[t2];
            }
    }
    #pragma unroll
    for (int k = 0; k < 50; ++k) {
        float v = acc[k];
        for (int m = 32; m > 0; m >>= 1) v += __shfl_xor(v, m, 64);
        acc[k] = v;
    }
    __shared__ float s_red[4][50];
    int lane = tid & 63, wid = tid >> 6;
    if (lane == 0) {
        #pragma unroll
        for (int k = 0; k < 50; ++k) s_red[wid][k] = acc[k];
    }
    __syncthreads();
    if (tid < 50) {
        gG[b*50 + tid] = s_red[0][tid] + s_red[1][tid] + s_red[2][tid] + s_red[3][tid];
    }
}

// ---------------- K3: 5x5 complex Hermitian Jacobi eigensolve -> W = V f(Lambda) V^H
__global__ void k_eig(const float* __restrict__ gG, const float* __restrict__ thres,
                      float* __restrict__ gW)
{
    int b = blockIdx.x * 64 + threadIdx.x;
    if (b >= 80) return;
    float Ar[5][5], Ai[5][5], Vr[5][5], Vi[5][5];
    #pragma unroll
    for (int a = 0; a < 5; ++a)
        #pragma unroll
        for (int c = 0; c < 5; ++c) {
            Ar[a][c] = gG[b*50 + (a*5+c)*2];
            Ai[a][c] = gG[b*50 + (a*5+c)*2 + 1];
            Vr[a][c] = (a==c) ? 1.f : 0.f;
            Vi[a][c] = 0.f;
        }
    for (int sw = 0; sw < 9; ++sw) {
        #pragma unroll
        for (int p = 0; p < 4; ++p) {
            #pragma unroll
            for (int q = p+1; q < 5; ++q) {
                float apr = Ar[p][q], api = Ai[p][q];
                float n2 = apr*apr + api*api;
                if (n2 > 1e-24f) {
                    float mlen = sqrtf(n2);
                    float phr = apr / mlen, phi = api / mlen;
                    float tau = (Ar[q][q] - Ar[p][p]) / (2.f * mlen);
                    float tt = (tau >= 0.f ? 1.f : -1.f) / (fabsf(tau) + sqrtf(1.f + tau*tau));
                    float cc = 1.f / sqrtf(1.f + tt*tt);
                    float ss = tt * cc;
                    float wr2 = ss * phr, wi2 = ss * phi;   // w = s*e^{i phi}
                    #pragma unroll
                    for (int k = 0; k < 5; ++k) {
                        float xr = Ar[k][p], xi2 = Ai[k][p];
                        float yr = Ar[k][q], yi = Ai[k][q];
                        Ar[k][p] = cc*xr - (wr2*yr + wi2*yi);
                        Ai[k][p] = cc*xi2 - (wr2*yi - wi2*yr);
                        Ar[k][q] = wr2*xr - wi2*xi2 + cc*yr;
                        Ai[k][q] = wr2*xi2 + wi2*xr + cc*yi;
                        float vxr = Vr[k][p], vxi = Vi[k][p];
                        float vyr = Vr[k][q], vyi = Vi[k][q];
                        Vr[k][p] = cc*vxr - (wr2*vyr + wi2*vyi);
                        Vi[k][p] = cc*vxi - (wr2*vyi - wi2*vyr);
                        Vr[k][q] = wr2*vxr - wi2*vxi + cc*vyr;
                        Vi[k][q] = wr2*vxi + wi2*vxr + cc*vyi;
                    }
                    #pragma unroll
                    for (int k = 0; k < 5; ++k) {
                        float xr = Ar[p][k], xi2 = Ai[p][k];
                        float yr = Ar[q][k], yi = Ai[q][k];
                        Ar[p][k] = cc*xr - (wr2*yr - wi2*yi);
                        Ai[p][k] = cc*xi2 - (wr2*yi + wi2*yr);
                        Ar[q][k] = wr2*xr + wi2*xi2 + cc*yr;
                        Ai[q][k] = wr2*xi2 - wi2*xr + cc*yi;
                    }
                }
            }
        }
    }
    float sv[5], s0 = 0.f;
    #pragma unroll
    for (int k = 0; k < 5; ++k) { sv[k] = sqrtf(fmaxf(Ar[k][k], 0.f)); s0 = fmaxf(s0, sv[k]); }
    float th = fmaxf(thres[b], 0.f) * s0;
    float ratio[5];
    #pragma unroll
    for (int k = 0; k < 5; ++k)
        ratio[k] = sv[k] > 0.f ? fmaxf(sv[k] - th, 0.f) / sv[k] : 0.f;
    #pragma unroll
    for (int a = 0; a < 5; ++a)
        #pragma unroll
        for (int c = 0; c < 5; ++c) {
            float wr = 0.f, wi = 0.f;
            #pragma unroll
            for (int k = 0; k < 5; ++k) {
                wr += ratio[k] * (Vr[a][k]*Vr[c][k] + Vi[a][k]*Vi[c][k]);
                wi += ratio[k] * (Vi[a][k]*Vr[c][k] - Vr[a][k]*Vi[c][k]);
            }
            gW[b*50 + (a*5+c)*2]   = wr;
            gW[b*50 + (a*5+c)*2+1] = wi;
        }
}

// ---------------- K3b: region-averaged W (7x7 overlap regions per chunk), includes 1/cnt
__global__ void k_wavg(const float* __restrict__ gW, float* __restrict__ gA)
{
    int blk = blockIdx.x;         // chunk*49 + rx*7 + ry
    int e = threadIdx.x;
    if (e >= 25) return;
    int chunk = blk / 49;
    int rem = blk % 49;
    int rx = rem / 7, ry = rem % 7;
    int i0 = rx >> 1, i1 = (rx + 1) >> 1;
    int j0 = ry >> 1, j1 = (ry + 1) >> 1;
    float sr = 0.f, si = 0.f; int cnt = 0;
    for (int i = i0; i <= i1; ++i)
        for (int j = j0; j <= j1; ++j) {
            int b = chunk*16 + i*4 + j;
            sr += gW[b*50 + e*2];
            si += gW[b*50 + e*2 + 1];
            ++cnt;
        }
    float inv = 1.f / (float)cnt;
    gA[blk*50 + e*2]   = sr * inv;
    gA[blk*50 + e*2+1] = si * inv;
}

// ---------------- K4: q_re = Re(Wavg * x5) ; out += q_re*(1-p_w)   (fp32 RMW)
__global__ __launch_bounds__(256) void k_final(
    const float* __restrict__ re, const float* __restrict__ im,
    const float* __restrict__ gA, const float* __restrict__ p_w,
    float* __restrict__ out)
{
    int pix = blockIdx.x * 256 + threadIdx.x;
    int chunk = blockIdx.y;
    int X = pix / NXY, Y = pix % NXY;
    int i_lo = (X - 4) / SXY; if (i_lo < 0) i_lo = 0;
    int i_hi = X / SXY;       if (i_hi > 3) i_hi = 3;
    int j_lo = (Y - 4) / SXY; if (j_lo < 0) j_lo = 0;
    int j_hi = Y / SXY;       if (j_hi > 3) j_hi = 3;
    int rx = i_lo + i_hi, ry = j_lo + j_hi;
    const float* wa = gA + (size_t)(chunk*49 + rx*7 + ry) * 50;
    float Wr[5][5], Wi[5][5];
    #pragma unroll
    for (int a = 0; a < 5; ++a)
        #pragma unroll
        for (int r = 0; r < 5; ++r) {
            Wr[a][r] = wa[(a*5+r)*2];
            Wi[a][r] = wa[(a*5+r)*2+1];
        }
    float xr[5], xi[5];
    #pragma unroll
    for (int r = 0; r < 5; ++r) {
        size_t a = (size_t)(chunk*5+r)*NPIX + pix;
        xr[r] = re[a]; xi[r] = im[a];
    }
    float qwv = 1.f - p_w[0];
    #pragma unroll
    for (int tl = 0; tl < 5; ++tl) {
        float qr = 0.f;
        #pragma unroll
        for (int r = 0; r < 5; ++r)
            qr += Wr[tl][r]*xr[r] - Wi[tl][r]*xi[r];
        size_t idx = (size_t)(chunk*5+tl)*NPIX + pix;
        out[idx] += qr*qwv;
    }
}

extern "C" void kernel_launch(void* const* d_in, const int* in_sizes, int n_in,
                              void* d_out, int out_size, void* d_ws, size_t ws_size,
                              hipStream_t stream)
{
    const float* re    = (const float*)d_in[0];
    const float* im    = (const float*)d_in[1];
    const float* w1r   = (const float*)d_in[2];
    const float* w1i   = (const float*)d_in[3];
    const float* b1r   = (const float*)d_in[4];
    const float* b1i   = (const float*)d_in[5];
    const float* w2r   = (const float*)d_in[6];
    const float* w2i   = (const float*)d_in[7];
    const float* b2r   = (const float*)d_in[8];
    const float* b2i   = (const float*)d_in[9];
    const float* w3r   = (const float*)d_in[10];
    const float* w3i   = (const float*)d_in[11];
    const float* b3r   = (const float*)d_in[12];
    const float* thres = (const float*)d_in[14];
    const float* tau_w = (const float*)d_in[15];
    const float* p_w   = (const float*)d_in[16];
    const int* num_iter= (const int*)d_in[17];

    float* ws = (float*)d_ws;
    float* wt1 = ws;                // 600 floats (300 vf2)
    float* wt2 = wt1 + 600;         // 864 floats (432 vf2)
    float* gG  = wt2 + 864;         // 80*50 floats
    float* gW  = gG + 80*50;        // 80*50 floats
    float* gA  = gW + 80*50;        // 245*50 floats  (total ~87 KB)

    float* outf = (float*)d_out;

    k_prep<<<2, 256, 0, stream>>>(w1r, w1i, w2r, w2i, wt1, wt2);
    dim3 g1(NXY/TW, NXY/TH);
    k_conv<<<g1, 256, 0, stream>>>(re, im, (const vf2*)wt1, (const vf2*)wt2,
                                   b1r, b1i, b2r, b2i, w3r, w3i, b3r,
                                   tau_w, p_w, num_iter, outf);
    k_gram<<<80, 256, 0, stream>>>(re, im, gG);
    k_eig<<<2, 64, 0, stream>>>(gG, thres, gW);
    k_wavg<<<245, 32, 0, stream>>>(gW, gA);
    dim3 g4(NPIX/256, 5);
    k_final<<<g4, 256, 0, stream>>>(re, im, gA, p_w, outf);
}

// Round 2
// 502.630 us; speedup vs baseline: 1.5085x; 1.2839x over previous
//
#include <hip/hip_runtime.h>
#include <hip/hip_fp16.h>

#define NT 25
#define NXY 448
#define NPIX (448*448)
#define PXY 115
#define SXY 111

#define TW 32
#define TH 8
#define CH 5          // output frames per time-chunk
#define NZ 5          // number of time chunks (NT/CH)
#define GSL 8         // k_gram spatial slices

typedef float vf2 __attribute__((ext_vector_type(2)));

// complex MAC via packed fp32: z += x * w  (z,x,w are (re,im) pairs)
//  pk1: z.lo += x.lo*w.lo ; z.hi += x.lo*w.hi      (xr*wr, xr*wi)
//  pk2: z.lo += -x.hi*w.hi ; z.hi += x.hi*w.lo     (-xi*wi, xi*wr)
// weight operand comes from an SGPR pair (wave-uniform) -> zero DS/VALU cost to source it
#define CMACS(z, x, w)                                                                             \
    asm("v_pk_fma_f32 %0, %1, %2, %0 op_sel:[0,0,0] op_sel_hi:[0,1,1]"                             \
        : "+v"(z) : "v"(x), "s"(w));                                                               \
    asm("v_pk_fma_f32 %0, %1, %2, %0 op_sel:[1,1,0] op_sel_hi:[1,0,1] neg_lo:[0,1,0]"              \
        : "+v"(z) : "v"(x), "s"(w));

// ---------------- K0: transpose weights into (tap-major, channel-contiguous) vf2 layout
__global__ void k_prep(const float* __restrict__ w1r, const float* __restrict__ w1i,
                       const float* __restrict__ w2r, const float* __restrict__ w2i,
                       float* __restrict__ wt1, float* __restrict__ wt2)
{
    int i = blockIdx.x * 256 + threadIdx.x;
    if (i < 300) {
        int c = i / 25, tap = i - c * 25;
        wt1[(tap*12 + c)*2]     = w1r[i];
        wt1[(tap*12 + c)*2 + 1] = w1i[i];
    }
    if (i < 432) {
        int dt = i % 3; int t = i / 3; int c1 = t % 12; int c2 = t / 12;
        wt2[((c1*3+dt)*12 + c2)*2]     = w2r[i];
        wt2[((c1*3+dt)*12 + c2)*2 + 1] = w2i[i];
    }
}

// ---------------- K1: fused complex conv1(1->12,5x5)+ReLU -> conv2(12->12,3 temporal)+ReLU
// -> conv3(12->1) real part ; out = (x_re - denR*tsc)*pwv   (fp32, [25,448,448])
// Time-chunked (gridDim.z = NZ, 5 output frames/block, 2 halo conv1 recomputes) for
// occupancy; async-STAGE split (global->reg issued BEFORE compute, reg->LDS + single
// barrier after) hides HBM latency under the MAC stream.
__global__ __launch_bounds__(256, 4) void k_conv(
    const float* __restrict__ re, const float* __restrict__ im,
    const vf2* __restrict__ wt1, const vf2* __restrict__ wt2,
    const float* __restrict__ b1r, const float* __restrict__ b1i,
    const float* __restrict__ b2r, const float* __restrict__ b2i,
    const float* __restrict__ w3r, const float* __restrict__ w3i,
    const float* __restrict__ b3r,
    const float* __restrict__ tau_w, const float* __restrict__ p_w,
    const int* __restrict__ num_iter,
    float* __restrict__ out)
{
    __shared__ vf2 s_b1v[12], s_b2v[12];
    __shared__ float s_w3r[12], s_w3i[12], s_b3[1];
    __shared__ vf2 s_inv[2][12*36];       // double-buffered input tile (re,im), 2-halo

    const int tid = threadIdx.x;
    const int tx = tid & 31;
    const int ty = tid >> 5;
    const int Y0 = blockIdx.x * TW;
    const int X0 = blockIdx.y * TH;
    const int z  = blockIdx.z;            // time chunk
    const int z0 = z * CH;                // first output frame of this chunk
    const int fs = (z == 0) ? 0 : z0 - 1; // first conv1 frame
    const int fe = (z0 + CH < NT) ? z0 + CH : NT - 1;  // last conv1 frame

    if (tid < 12) {
        s_b1v[tid] = (vf2){b1r[tid], b1i[tid]};
        s_b2v[tid] = (vf2){b2r[tid], b2i[tid]};
        s_w3r[tid] = w3r[tid]; s_w3i[tid] = w3i[tid];
    }
    if (tid == 0) s_b3[0] = b3r[0];

    const float tsc = fmaxf(tau_w[0], 0.f) / (float)num_iter[0];
    const float pwv = fmaxf(p_w[0], 0.f);

    // staging geometry (frame-independent): item0 = tid, item1 = tid+256 (if < 432)
    const int idx1 = tid + 256;
    int r0 = tid / 36, c0 = tid - r0*36;
    int gx0 = X0 + r0 - 2, gy0 = Y0 + c0 - 2;
    bool k0 = (gx0 >= 0) && (gx0 < NXY) && (gy0 >= 0) && (gy0 < NXY);
    const int a0 = (k0 ? gx0 : 0) * NXY + (k0 ? gy0 : 0);
    const float m0 = k0 ? 1.f : 0.f;
    int r1 = idx1 / 36, c1_ = idx1 - r1*36;
    int gx1 = X0 + r1 - 2, gy1 = Y0 + c1_ - 2;
    bool k1 = (gx1 >= 0) && (gx1 < NXY) && (gy1 >= 0) && (gy1 < NXY);
    const int a1 = (k1 ? gx1 : 0) * NXY + (k1 ? gy1 : 0);
    const float m1 = k1 ? 1.f : 0.f;

    // persistent h1 slots: hA = h[t-1], hB = h[t], hC = h[t+1] (relu'd, fp16 pairs)
    __half2 hA[12], hB[12], hC[12];
    #pragma unroll
    for (int c = 0; c < 12; ++c) { hA[c] = __half2{}; hB[c] = __half2{}; hC[c] = __half2{}; }

    // conv1 for frame tf -> relu -> fp16-pack into hs (register array, static indexing)
    auto conv1_to = [&](int tf, __half2 (&hs)[12]) {
        vf2 a[12];
        #pragma unroll
        for (int c = 0; c < 12; ++c) a[c] = s_b1v[c];
        const vf2* sin_ = s_inv[tf & 1];
        #pragma unroll 1
        for (int ky = 0; ky < 5; ++ky) {
            const vf2* irow = &sin_[(ty+ky)*36 + tx];
            const vf2* wrow = &wt1[ky*5*12];
            #pragma unroll
            for (int kx = 0; kx < 5; ++kx) {
                vf2 x = irow[kx];
                const vf2* wp = wrow + kx*12;
                #pragma unroll
                for (int c = 0; c < 12; ++c) { vf2 w = wp[c]; CMACS(a[c], x, w); }
            }
        }
        #pragma unroll
        for (int c = 0; c < 12; ++c)
            hs[c] = __floats2half2_rn(fmaxf(a[c].x,0.f), fmaxf(a[c].y,0.f));
    };

    // conv2(+ReLU)+conv3+epilogue for output frame tc
    auto do_out = [&](int tc, __half2 (&hp)[12], __half2 (&hc)[12], __half2 (&hn)[12],
                      bool hasP, bool hasN) {
        vf2 zz[12];
        #pragma unroll
        for (int c = 0; c < 12; ++c) zz[c] = s_b2v[c];
        if (hasP) {
            #pragma unroll
            for (int c1 = 0; c1 < 12; ++c1) {
                vf2 x = (vf2){__low2float(hp[c1]), __high2float(hp[c1])};
                const vf2* wp = &wt2[(c1*3+0)*12];
                #pragma unroll
                for (int c2 = 0; c2 < 12; ++c2) { vf2 w = wp[c2]; CMACS(zz[c2], x, w); }
            }
        }
        {
            #pragma unroll
            for (int c1 = 0; c1 < 12; ++c1) {
                vf2 x = (vf2){__low2float(hc[c1]), __high2float(hc[c1])};
                const vf2* wp = &wt2[(c1*3+1)*12];
                #pragma unroll
                for (int c2 = 0; c2 < 12; ++c2) { vf2 w = wp[c2]; CMACS(zz[c2], x, w); }
            }
        }
        if (hasN) {
            #pragma unroll
            for (int c1 = 0; c1 < 12; ++c1) {
                vf2 x = (vf2){__low2float(hn[c1]), __high2float(hn[c1])};
                const vf2* wp = &wt2[(c1*3+2)*12];
                #pragma unroll
                for (int c2 = 0; c2 < 12; ++c2) { vf2 w = wp[c2]; CMACS(zz[c2], x, w); }
            }
        }
        float dR = s_b3[0];
        #pragma unroll
        for (int c = 0; c < 12; ++c)
            dR += fmaxf(zz[c].x,0.f)*s_w3r[c] - fmaxf(zz[c].y,0.f)*s_w3i[c];
        size_t idx = (size_t)tc*NPIX + (size_t)(X0+ty)*NXY + (Y0+tx);
        out[idx] = (re[idx] - dR * tsc) * pwv;
    };

    // prologue: stage frame fs
    {
        const float* rp = re + (size_t)fs * NPIX;
        const float* ip = im + (size_t)fs * NPIX;
        float pr0 = rp[a0], pi0 = ip[a0];
        float pr1 = 0.f, pi1 = 0.f;
        if (idx1 < 432) { pr1 = rp[a1]; pi1 = ip[a1]; }
        vf2* dst = s_inv[fs & 1];
        dst[tid] = (vf2){pr0*m0, pi0*m0};
        if (idx1 < 432) dst[idx1] = (vf2){pr1*m1, pi1*m1};
    }
    __syncthreads();

    #pragma unroll 1
    for (int f = fs; f <= fe; ++f) {
        // (1) issue next frame's loads early -> regs (latency hides under compute)
        float pr0 = 0.f, pi0 = 0.f, pr1 = 0.f, pi1 = 0.f;
        const bool more = (f < fe);
        if (more) {
            const float* rp = re + (size_t)(f+1) * NPIX;
            const float* ip = im + (size_t)(f+1) * NPIX;
            pr0 = rp[a0]; pi0 = ip[a0];
            if (idx1 < 432) { pr1 = rp[a1]; pi1 = ip[a1]; }
        }
        // (2) compute on already-staged frame f
        conv1_to(f, hC);
        const int tc = f - 1;
        if (f > fs && tc >= z0)
            do_out(tc, hA, hB, hC, tc >= 1, true);
        // (3) write prefetched regs to the other LDS buffer, then one barrier
        if (more) {
            vf2* dst = s_inv[(f+1) & 1];
            dst[tid] = (vf2){pr0*m0, pi0*m0};
            if (idx1 < 432) dst[idx1] = (vf2){pr1*m1, pi1*m1};
        }
        __syncthreads();
        #pragma unroll
        for (int c = 0; c < 12; ++c) { hA[c] = hB[c]; hB[c] = hC[c]; }
    }
    // final frame of the last chunk: tc = 24, no next frame
    if (fe == NT - 1)
        do_out(NT - 1, hA, hB, hC, true, false);
}

// ---------------- K2: Gram partials  gP[(b*GSL+slice)*50 + k]  (deterministic fold in k_eig)
__global__ __launch_bounds__(256) void k_gram(
    const float* __restrict__ re, const float* __restrict__ im,
    float* __restrict__ gP)
{
    const int b = blockIdx.x;            // 0..79  = chunk*16 + i*4 + j
    const int slice = blockIdx.y;        // 0..GSL-1
    const int chunk = b >> 4;
    const int pidx = b & 15;
    const int X0 = (pidx >> 2) * SXY;
    const int Y0 = (pidx & 3) * SXY;
    const int tid = threadIdx.x;

    float acc[50];
    #pragma unroll
    for (int k = 0; k < 50; ++k) acc[k] = 0.f;

    const int npx = PXY * PXY;           // 13225
    for (int pi = slice*256 + tid; pi < npx; pi += 256*GSL) {
        int px = pi / PXY, py = pi % PXY;
        size_t base = (size_t)(X0 + px) * NXY + (Y0 + py);
        float xr[5], xi[5];
        #pragma unroll
        for (int r = 0; r < 5; ++r) {
            size_t a = (size_t)(chunk*5 + r) * NPIX + base;
            xr[r] = re[a]; xi[r] = im[a];
        }
        #pragma unroll
        for (int t1 = 0; t1 < 5; ++t1)
            #pragma unroll
            for (int t2 = 0; t2 < 5; ++t2) {
                acc[(t1*5+t2)*2]   += xr[t1]*xr[t2] + xi[t1]*xi[t2];
                acc[(t1*5+t2)*2+1] += xi[t1]*xr[t2] - xr[t1]*xi[t2];
            }
    }
    #pragma unroll
    for (int k = 0; k < 50; ++k) {
        float v = acc[k];
        for (int m = 32; m > 0; m >>= 1) v += __shfl_xor(v, m, 64);
        acc[k] = v;
    }
    __shared__ float s_red[4][50];
    int lane = tid & 63, wid = tid >> 6;
    if (lane == 0) {
        #pragma unroll
        for (int k = 0; k < 50; ++k) s_red[wid][k] = acc[k];
    }
    __syncthreads();
    if (tid < 50) {
        gP[(b*GSL + slice)*50 + tid] =
            s_red[0][tid] + s_red[1][tid] + s_red[2][tid] + s_red[3][tid];
    }
}

// ---------------- K3: fold Gram partials + 5x5 complex Hermitian Jacobi -> W = V f(L) V^H
__global__ void k_eig(const float* __restrict__ gP, const float* __restrict__ thres,
                      float* __restrict__ gW)
{
    int b = blockIdx.x * 64 + threadIdx.x;
    if (b >= 80) return;
    float Ar[5][5], Ai[5][5], Vr[5][5], Vi[5][5];
    #pragma unroll
    for (int a = 0; a < 5; ++a)
        #pragma unroll
        for (int c = 0; c < 5; ++c) {
            float sr = 0.f, si = 0.f;
            #pragma unroll
            for (int sl = 0; sl < GSL; ++sl) {
                sr += gP[(b*GSL + sl)*50 + (a*5+c)*2];
                si += gP[(b*GSL + sl)*50 + (a*5+c)*2 + 1];
            }
            Ar[a][c] = sr;
            Ai[a][c] = si;
            Vr[a][c] = (a==c) ? 1.f : 0.f;
            Vi[a][c] = 0.f;
        }
    for (int sw = 0; sw < 9; ++sw) {
        #pragma unroll
        for (int p = 0; p < 4; ++p) {
            #pragma unroll
            for (int q = p+1; q < 5; ++q) {
                float apr = Ar[p][q], api = Ai[p][q];
                float n2 = apr*apr + api*api;
                if (n2 > 1e-24f) {
                    float mlen = sqrtf(n2);
                    float phr = apr / mlen, phi = api / mlen;
                    float tau = (Ar[q][q] - Ar[p][p]) / (2.f * mlen);
                    float tt = (tau >= 0.f ? 1.f : -1.f) / (fabsf(tau) + sqrtf(1.f + tau*tau));
                    float cc = 1.f / sqrtf(1.f + tt*tt);
                    float ss = tt * cc;
                    float wr2 = ss * phr, wi2 = ss * phi;   // w = s*e^{i phi}
                    #pragma unroll
                    for (int k = 0; k < 5; ++k) {
                        float xr = Ar[k][p], xi2 = Ai[k][p];
                        float yr = Ar[k][q], yi = Ai[k][q];
                        Ar[k][p] = cc*xr - (wr2*yr + wi2*yi);
                        Ai[k][p] = cc*xi2 - (wr2*yi - wi2*yr);
                        Ar[k][q] = wr2*xr - wi2*xi2 + cc*yr;
                        Ai[k][q] = wr2*xi2 + wi2*xr + cc*yi;
                        float vxr = Vr[k][p], vxi = Vi[k][p];
                        float vyr = Vr[k][q], vyi = Vi[k][q];
                        Vr[k][p] = cc*vxr - (wr2*vyr + wi2*vyi);
                        Vi[k][p] = cc*vxi - (wr2*vyi - wi2*vyr);
                        Vr[k][q] = wr2*vxr - wi2*vxi + cc*vyr;
                        Vi[k][q] = wr2*vxi + wi2*vxr + cc*vyi;
                    }
                    #pragma unroll
                    for (int k = 0; k < 5; ++k) {
                        float xr = Ar[p][k], xi2 = Ai[p][k];
                        float yr = Ar[q][k], yi = Ai[q][k];
                        Ar[p][k] = cc*xr - (wr2*yr - wi2*yi);
                        Ai[p][k] = cc*xi2 - (wr2*yi + wi2*yr);
                        Ar[q][k] = wr2*xr + wi2*xi2 + cc*yr;
                        Ai[q][k] = wr2*xi2 - wi2*xr + cc*yi;
                    }
                }
            }
        }
    }
    float sv[5], s0 = 0.f;
    #pragma unroll
    for (int k = 0; k < 5; ++k) { sv[k] = sqrtf(fmaxf(Ar[k][k], 0.f)); s0 = fmaxf(s0, sv[k]); }
    float th = fmaxf(thres[b], 0.f) * s0;
    float ratio[5];
    #pragma unroll
    for (int k = 0; k < 5; ++k)
        ratio[k] = sv[k] > 0.f ? fmaxf(sv[k] - th, 0.f) / sv[k] : 0.f;
    #pragma unroll
    for (int a = 0; a < 5; ++a)
        #pragma unroll
        for (int c = 0; c < 5; ++c) {
            float wr = 0.f, wi = 0.f;
            #pragma unroll
            for (int k = 0; k < 5; ++k) {
                wr += ratio[k] * (Vr[a][k]*Vr[c][k] + Vi[a][k]*Vi[c][k]);
                wi += ratio[k] * (Vi[a][k]*Vr[c][k] - Vr[a][k]*Vi[c][k]);
            }
            gW[b*50 + (a*5+c)*2]   = wr;
            gW[b*50 + (a*5+c)*2+1] = wi;
        }
}

// ---------------- K3b: region-averaged W (7x7 overlap regions per chunk), includes 1/cnt
__global__ void k_wavg(const float* __restrict__ gW, float* __restrict__ gA)
{
    int blk = blockIdx.x;         // chunk*49 + rx*7 + ry
    int e = threadIdx.x;
    if (e >= 25) return;
    int chunk = blk / 49;
    int rem = blk % 49;
    int rx = rem / 7, ry = rem % 7;
    int i0 = rx >> 1, i1 = (rx + 1) >> 1;
    int j0 = ry >> 1, j1 = (ry + 1) >> 1;
    float sr = 0.f, si = 0.f; int cnt = 0;
    for (int i = i0; i <= i1; ++i)
        for (int j = j0; j <= j1; ++j) {
            int b = chunk*16 + i*4 + j;
            sr += gW[b*50 + e*2];
            si += gW[b*50 + e*2 + 1];
            ++cnt;
        }
    float inv = 1.f / (float)cnt;
    gA[blk*50 + e*2]   = sr * inv;
    gA[blk*50 + e*2+1] = si * inv;
}

// ---------------- K4: q_re = Re(Wavg * x5) ; out += q_re*(1-p_w)   (fp32 RMW)
__global__ __launch_bounds__(256) void k_final(
    const float* __restrict__ re, const float* __restrict__ im,
    const float* __restrict__ gA, const float* __restrict__ p_w,
    float* __restrict__ out)
{
    int pix = blockIdx.x * 256 + threadIdx.x;
    int chunk = blockIdx.y;
    int X = pix / NXY, Y = pix % NXY;
    int i_lo = (X - 4) / SXY; if (i_lo < 0) i_lo = 0;
    int i_hi = X / SXY;       if (i_hi > 3) i_hi = 3;
    int j_lo = (Y - 4) / SXY; if (j_lo < 0) j_lo = 0;
    int j_hi = Y / SXY;       if (j_hi > 3) j_hi = 3;
    int rx = i_lo + i_hi, ry = j_lo + j_hi;
    const float* wa = gA + (size_t)(chunk*49 + rx*7 + ry) * 50;
    float Wr[5][5], Wi[5][5];
    #pragma unroll
    for (int a = 0; a < 5; ++a)
        #pragma unroll
        for (int r = 0; r < 5; ++r) {
            Wr[a][r] = wa[(a*5+r)*2];
            Wi[a][r] = wa[(a*5+r)*2+1];
        }
    float xr[5], xi[5];
    #pragma unroll
    for (int r = 0; r < 5; ++r) {
        size_t a = (size_t)(chunk*5+r)*NPIX + pix;
        xr[r] = re[a]; xi[r] = im[a];
    }
    float qwv = 1.f - p_w[0];
    #pragma unroll
    for (int tl = 0; tl < 5; ++tl) {
        float qr = 0.f;
        #pragma unroll
        for (int r = 0; r < 5; ++r)
            qr += Wr[tl][r]*xr[r] - Wi[tl][r]*xi[r];
        size_t idx = (size_t)(chunk*5+tl)*NPIX + pix;
        out[idx] += qr*qwv;
    }
}

extern "C" void kernel_launch(void* const* d_in, const int* in_sizes, int n_in,
                              void* d_out, int out_size, void* d_ws, size_t ws_size,
                              hipStream_t stream)
{
    const float* re    = (const float*)d_in[0];
    const float* im    = (const float*)d_in[1];
    const float* w1r   = (const float*)d_in[2];
    const float* w1i   = (const float*)d_in[3];
    const float* b1r   = (const float*)d_in[4];
    const float* b1i   = (const float*)d_in[5];
    const float* w2r   = (const float*)d_in[6];
    const float* w2i   = (const float*)d_in[7];
    const float* b2r   = (const float*)d_in[8];
    const float* b2i   = (const float*)d_in[9];
    const float* w3r   = (const float*)d_in[10];
    const float* w3i   = (const float*)d_in[11];
    const float* b3r   = (const float*)d_in[12];
    const float* thres = (const float*)d_in[14];
    const float* tau_w = (const float*)d_in[15];
    const float* p_w   = (const float*)d_in[16];
    const int* num_iter= (const int*)d_in[17];

    float* ws = (float*)d_ws;
    float* wt1 = ws;                     // 600 floats (300 vf2)
    float* wt2 = wt1 + 600;              // 864 floats (432 vf2)
    float* gP  = wt2 + 864;              // 80*GSL*50 = 32000 floats
    float* gW  = gP + 80*GSL*50;         // 80*50 floats
    float* gA  = gW + 80*50;             // 245*50 floats  (total ~200 KB)

    float* outf = (float*)d_out;

    k_prep<<<2, 256, 0, stream>>>(w1r, w1i, w2r, w2i, wt1, wt2);
    dim3 g1(NXY/TW, NXY/TH, NZ);
    k_conv<<<g1, 256, 0, stream>>>(re, im, (const vf2*)wt1, (const vf2*)wt2,
                                   b1r, b1i, b2r, b2i, w3r, w3i, b3r,
                                   tau_w, p_w, num_iter, outf);
    dim3 g2(80, GSL);
    k_gram<<<g2, 256, 0, stream>>>(re, im, gP);
    k_eig<<<2, 64, 0, stream>>>(gP, thres, gW);
    k_wavg<<<245, 32, 0, stream>>>(gW, gA);
    dim3 g4(NPIX/256, 5);
    k_final<<<g4, 256, 0, stream>>>(re, im, gA, p_w, outf);
}

// Round 5
// 474.759 us; speedup vs baseline: 1.5971x; 1.0587x over previous
//
#include <hip/hip_runtime.h>
#include <hip/hip_fp16.h>

#define NT 25
#define NXY 448
#define NPIX (448*448)
#define PXY 115
#define SXY 111

#define TW 32
#define TH 8
#define CH 5          // output frames per time-chunk
#define NZ 5          // number of time chunks (NT/CH)
#define GSL 8         // gram spatial slices

typedef float vf2 __attribute__((ext_vector_type(2)));

// complex MAC via packed fp16 dot2 (full-rate packed-math pipe, f32 accumulate):
//  zr += xr*wr - xi*wi  = dot2(x=(xr,xi), wA=(wr,-wi))
//  zi += xr*wi + xi*wr  = dot2(x=(xr,xi), wB=(wi, wr))
// weight operand is wave-uniform -> SGPR source (1 sgpr read per instr, legal in VOP3P)
#define DOT2(acc, x, w)                                                                            \
    asm("v_dot2_f32_f16 %0, %1, %2, %0" : "+v"(acc) : "v"(x), "s"(w))

static __device__ __forceinline__ unsigned int packh2f(float lo, float hi) {
    auto h = __builtin_amdgcn_cvt_pkrtz(lo, hi);   // __fp16 ext_vector(2) -> v_cvt_pkrtz_f16_f32
    return __builtin_bit_cast(unsigned int, h);
}

// ---------------- K0: pack weights into fp16 dot2-pair layout
// wt1h[(tap*12+c)*2 + {0,1}] = pack(wr,-wi) / pack(wi,wr)   for w1[c*25+tap]
// wt2h[((c1*3+dt)*12+c2)*2 + {0,1}] likewise for w2[(c2*12+c1)*3+dt]
__global__ void k_prep(const float* __restrict__ w1r, const float* __restrict__ w1i,
                       const float* __restrict__ w2r, const float* __restrict__ w2i,
                       unsigned int* __restrict__ wt1h, unsigned int* __restrict__ wt2h)
{
    int i = blockIdx.x * 256 + threadIdx.x;
    auto pk = [](float a, float b) {
        unsigned short ua = __half_as_ushort(__float2half_rn(a));
        unsigned short ub = __half_as_ushort(__float2half_rn(b));
        return (unsigned int)ua | ((unsigned int)ub << 16);
    };
    if (i < 300) {
        int c = i / 25, tap = i - c * 25;
        wt1h[(tap*12 + c)*2]     = pk(w1r[i], -w1i[i]);
        wt1h[(tap*12 + c)*2 + 1] = pk(w1i[i],  w1r[i]);
    }
    if (i < 432) {
        int dt = i % 3; int t = i / 3; int c1 = t % 12; int c2 = t / 12;
        wt2h[((c1*3+dt)*12 + c2)*2]     = pk(w2r[i], -w2i[i]);
        wt2h[((c1*3+dt)*12 + c2)*2 + 1] = pk(w2i[i],  w2r[i]);
    }
}

// ---------------- K1 (merged): z<NZ -> fused conv pipeline; z==NZ -> gram partials.
// Conv: conv1(1->12,5x5)+ReLU -> conv2(12->12,3t)+ReLU -> conv3(12->1) real
//       out = (x_re - dR*tsc)*pwv.  All MACs are v_dot2_f32_f16 with SGPR weights.
// Gram blocks fill occupancy holes and save a launch gap.
__global__ __launch_bounds__(256, 6) void k_work(
    const float* __restrict__ re, const float* __restrict__ im,
    const unsigned int* __restrict__ wt1h, const unsigned int* __restrict__ wt2h,
    const float* __restrict__ b1r, const float* __restrict__ b1i,
    const float* __restrict__ b2r, const float* __restrict__ b2i,
    const float* __restrict__ w3r, const float* __restrict__ w3i,
    const float* __restrict__ b3r,
    const float* __restrict__ tau_w, const float* __restrict__ p_w,
    const int* __restrict__ num_iter,
    float* __restrict__ out, float* __restrict__ gP)
{
    __shared__ unsigned int s_inv[2][12*36];   // double-buffered fp16 (re,im) input tile
    __shared__ float s_red[4][50];             // gram path only

    const int tid = threadIdx.x;

    if (blockIdx.z == NZ) {
        // ---------------- gram path ----------------
        const int gid = blockIdx.x + 14 * blockIdx.y;
        if (gid >= 80 * GSL) return;
        const int b = gid >> 3;              // 0..79 = chunk*16 + i*4 + j
        const int slice = gid & 7;
        const int chunk = b >> 4;
        const int pidx = b & 15;
        const int X0 = (pidx >> 2) * SXY;
        const int Y0 = (pidx & 3) * SXY;

        float acc[50];
        #pragma unroll
        for (int k = 0; k < 50; ++k) acc[k] = 0.f;

        const int npx = PXY * PXY;           // 13225
        for (int pi = slice*256 + tid; pi < npx; pi += 256*GSL) {
            int px = pi / PXY, py = pi % PXY;
            size_t base = (size_t)(X0 + px) * NXY + (Y0 + py);
            float xr[5], xi[5];
            #pragma unroll
            for (int r = 0; r < 5; ++r) {
                size_t a = (size_t)(chunk*5 + r) * NPIX + base;
                xr[r] = re[a]; xi[r] = im[a];
            }
            #pragma unroll
            for (int t1 = 0; t1 < 5; ++t1)
                #pragma unroll
                for (int t2 = 0; t2 < 5; ++t2) {
                    acc[(t1*5+t2)*2]   += xr[t1]*xr[t2] + xi[t1]*xi[t2];
                    acc[(t1*5+t2)*2+1] += xi[t1]*xr[t2] - xr[t1]*xi[t2];
                }
        }
        #pragma unroll
        for (int k = 0; k < 50; ++k) {
            float v = acc[k];
            for (int m = 32; m > 0; m >>= 1) v += __shfl_xor(v, m, 64);
            acc[k] = v;
        }
        int lane = tid & 63, wid = tid >> 6;
        if (lane == 0) {
            #pragma unroll
            for (int k = 0; k < 50; ++k) s_red[wid][k] = acc[k];
        }
        __syncthreads();
        if (tid < 50) {
            gP[(b*GSL + slice)*50 + tid] =
                s_red[0][tid] + s_red[1][tid] + s_red[2][tid] + s_red[3][tid];
        }
        return;
    }

    // ---------------- conv path ----------------
    const int tx = tid & 31;
    const int ty = tid >> 5;
    const int Y0 = blockIdx.x * TW;
    const int X0 = blockIdx.y * TH;
    const int z  = blockIdx.z;            // time chunk
    const int z0 = z * CH;                // first output frame of this chunk
    const int fs = (z == 0) ? 0 : z0 - 1; // first conv1 frame
    const int fe = (z0 + CH < NT) ? z0 + CH : NT - 1;  // last conv1 frame

    // wave-uniform params -> SGPRs
    float rb1[12], ib1[12], rb2[12], ib2[12], rw3[12], iw3[12];
    #pragma unroll
    for (int c = 0; c < 12; ++c) {
        rb1[c] = b1r[c]; ib1[c] = b1i[c];
        rb2[c] = b2r[c]; ib2[c] = b2i[c];
        rw3[c] = w3r[c]; iw3[c] = w3i[c];
    }
    const float b3v = b3r[0];
    const float tsc = fmaxf(tau_w[0], 0.f) / (float)num_iter[0];
    const float pwv = fmaxf(p_w[0], 0.f);

    // staging geometry (frame-independent): item0 = tid, item1 = tid+256 (if < 432)
    const int idx1 = tid + 256;
    int r0 = tid / 36, c0 = tid - r0*36;
    int gx0 = X0 + r0 - 2, gy0 = Y0 + c0 - 2;
    bool k0 = (gx0 >= 0) && (gx0 < NXY) && (gy0 >= 0) && (gy0 < NXY);
    const int a0 = (k0 ? gx0 : 0) * NXY + (k0 ? gy0 : 0);
    const float m0 = k0 ? 1.f : 0.f;
    int r1 = idx1 / 36, c1_ = idx1 - r1*36;
    int gx1 = X0 + r1 - 2, gy1 = Y0 + c1_ - 2;
    bool k1 = (gx1 >= 0) && (gx1 < NXY) && (gy1 >= 0) && (gy1 < NXY);
    const int a1 = (k1 ? gx1 : 0) * NXY + (k1 ? gy1 : 0);
    const float m1 = k1 ? 1.f : 0.f;

    // persistent h1 slots (relu'd fp16 pairs): hA=h[t-1], hB=h[t], hC=h[t+1]
    unsigned int hA[12], hB[12], hC[12];
    #pragma unroll
    for (int c = 0; c < 12; ++c) { hA[c] = 0u; hB[c] = 0u; hC[c] = 0u; }

    // conv1 for frame tf -> relu -> fp16-pack into hs
    auto conv1_to = [&](int tf, unsigned int (&hs)[12]) {
        float ar[12], ai[12];
        #pragma unroll
        for (int c = 0; c < 12; ++c) { ar[c] = rb1[c]; ai[c] = ib1[c]; }
        const unsigned int* sin_ = s_inv[tf & 1];
        #pragma unroll 1
        for (int ky = 0; ky < 5; ++ky) {
            const unsigned int* irow = &sin_[(ty+ky)*36 + tx];
            const unsigned int* wrow = &wt1h[ky*5*24];
            #pragma unroll
            for (int kx = 0; kx < 5; ++kx) {
                unsigned int x = irow[kx];
                const unsigned int* wp = wrow + kx*24;
                #pragma unroll
                for (int c = 0; c < 12; ++c) {
                    unsigned int wa = wp[c*2], wb = wp[c*2+1];
                    DOT2(ar[c], x, wa);
                    DOT2(ai[c], x, wb);
                }
            }
        }
        #pragma unroll
        for (int c = 0; c < 12; ++c)
            hs[c] = packh2f(fmaxf(ar[c],0.f), fmaxf(ai[c],0.f));
    };

    // conv2(+ReLU)+conv3+epilogue for output frame tc
    auto do_out = [&](int tc, unsigned int (&hp)[12], unsigned int (&hc)[12],
                      unsigned int (&hn)[12], bool hasP, bool hasN) {
        size_t idx = (size_t)tc*NPIX + (size_t)(X0+ty)*NXY + (Y0+tx);
        float reval = re[idx];             // issue early, hides under MACs
        float zr[12], zi[12];
        #pragma unroll
        for (int c = 0; c < 12; ++c) { zr[c] = rb2[c]; zi[c] = ib2[c]; }
        if (hasP) {
            #pragma unroll
            for (int c1 = 0; c1 < 12; ++c1) {
                unsigned int x = hp[c1];
                const unsigned int* wp = &wt2h[(c1*3+0)*24];
                #pragma unroll
                for (int c2 = 0; c2 < 12; ++c2) {
                    unsigned int wa = wp[c2*2], wb = wp[c2*2+1];
                    DOT2(zr[c2], x, wa);
                    DOT2(zi[c2], x, wb);
                }
            }
        }
        {
            #pragma unroll
            for (int c1 = 0; c1 < 12; ++c1) {
                unsigned int x = hc[c1];
                const unsigned int* wp = &wt2h[(c1*3+1)*24];
                #pragma unroll
                for (int c2 = 0; c2 < 12; ++c2) {
                    unsigned int wa = wp[c2*2], wb = wp[c2*2+1];
                    DOT2(zr[c2], x, wa);
                    DOT2(zi[c2], x, wb);
                }
            }
        }
        if (hasN) {
            #pragma unroll
            for (int c1 = 0; c1 < 12; ++c1) {
                unsigned int x = hn[c1];
                const unsigned int* wp = &wt2h[(c1*3+2)*24];
                #pragma unroll
                for (int c2 = 0; c2 < 12; ++c2) {
                    unsigned int wa = wp[c2*2], wb = wp[c2*2+1];
                    DOT2(zr[c2], x, wa);
                    DOT2(zi[c2], x, wb);
                }
            }
        }
        float dR = b3v;
        #pragma unroll
        for (int c = 0; c < 12; ++c)
            dR += fmaxf(zr[c],0.f)*rw3[c] - fmaxf(zi[c],0.f)*iw3[c];
        out[idx] = (reval - dR * tsc) * pwv;
    };

    // prologue: stage frame fs
    {
        const float* rp = re + (size_t)fs * NPIX;
        const float* ip = im + (size_t)fs * NPIX;
        float pr0 = rp[a0], pi0 = ip[a0];
        float pr1 = 0.f, pi1 = 0.f;
        if (idx1 < 432) { pr1 = rp[a1]; pi1 = ip[a1]; }
        unsigned int* dst = s_inv[fs & 1];
        dst[tid] = packh2f(pr0*m0, pi0*m0);
        if (idx1 < 432) dst[idx1] = packh2f(pr1*m1, pi1*m1);
    }
    __syncthreads();

    #pragma unroll 1
    for (int f = fs; f <= fe; ++f) {
        // (1) issue next frame's loads early -> regs (latency hides under compute)
        float pr0 = 0.f, pi0 = 0.f, pr1 = 0.f, pi1 = 0.f;
        const bool more = (f < fe);
        if (more) {
            const float* rp = re + (size_t)(f+1) * NPIX;
            const float* ip = im + (size_t)(f+1) * NPIX;
            pr0 = rp[a0]; pi0 = ip[a0];
            if (idx1 < 432) { pr1 = rp[a1]; pi1 = ip[a1]; }
        }
        // (2) compute on already-staged frame f
        conv1_to(f, hC);
        const int tc = f - 1;
        if (f > fs && tc >= z0)
            do_out(tc, hA, hB, hC, tc >= 1, true);
        // (3) write prefetched regs to the other LDS buffer, then one barrier
        if (more) {
            unsigned int* dst = s_inv[(f+1) & 1];
            dst[tid] = packh2f(pr0*m0, pi0*m0);
            if (idx1 < 432) dst[idx1] = packh2f(pr1*m1, pi1*m1);
        }
        __syncthreads();
        #pragma unroll
        for (int c = 0; c < 12; ++c) { hA[c] = hB[c]; hB[c] = hC[c]; }
    }
    // final frame of the last chunk: tc = 24
    if (fe == NT - 1)
        do_out(NT - 1, hA, hB, hC, true, false);
}

// ---------------- K2: fold Gram partials -> Jacobi eig -> W (LDS) -> region-avg gA
__global__ __launch_bounds__(128) void k_post(
    const float* __restrict__ gP, const float* __restrict__ thres,
    float* __restrict__ gA)
{
    __shared__ float sW[80*50];
    const int tid = threadIdx.x;
    if (tid < 80) {
        const int b = tid;
        float Ar[5][5], Ai[5][5], Vr[5][5], Vi[5][5];
        #pragma unroll
        for (int a = 0; a < 5; ++a)
            #pragma unroll
            for (int c = 0; c < 5; ++c) {
                float sr = 0.f, si = 0.f;
                #pragma unroll
                for (int sl = 0; sl < GSL; ++sl) {
                    sr += gP[(b*GSL + sl)*50 + (a*5+c)*2];
                    si += gP[(b*GSL + sl)*50 + (a*5+c)*2 + 1];
                }
                Ar[a][c] = sr; Ai[a][c] = si;
                Vr[a][c] = (a==c) ? 1.f : 0.f;
                Vi[a][c] = 0.f;
            }
        for (int sw = 0; sw < 9; ++sw) {
            #pragma unroll
            for (int p = 0; p < 4; ++p) {
                #pragma unroll
                for (int q = p+1; q < 5; ++q) {
                    float apr = Ar[p][q], api = Ai[p][q];
                    float n2 = apr*apr + api*api;
                    if (n2 > 1e-24f) {
                        float mlen = sqrtf(n2);
                        float phr = apr / mlen, phi = api / mlen;
                        float tau = (Ar[q][q] - Ar[p][p]) / (2.f * mlen);
                        float tt = (tau >= 0.f ? 1.f : -1.f) / (fabsf(tau) + sqrtf(1.f + tau*tau));
                        float cc = 1.f / sqrtf(1.f + tt*tt);
                        float ss = tt * cc;
                        float wr2 = ss * phr, wi2 = ss * phi;
                        #pragma unroll
                        for (int k = 0; k < 5; ++k) {
                            float xr = Ar[k][p], xi2 = Ai[k][p];
                            float yr = Ar[k][q], yi = Ai[k][q];
                            Ar[k][p] = cc*xr - (wr2*yr + wi2*yi);
                            Ai[k][p] = cc*xi2 - (wr2*yi - wi2*yr);
                            Ar[k][q] = wr2*xr - wi2*xi2 + cc*yr;
                            Ai[k][q] = wr2*xi2 + wi2*xr + cc*yi;
                            float vxr = Vr[k][p], vxi = Vi[k][p];
                            float vyr = Vr[k][q], vyi = Vi[k][q];
                            Vr[k][p] = cc*vxr - (wr2*vyr + wi2*vyi);
                            Vi[k][p] = cc*vxi - (wr2*vyi - wi2*vyr);
                            Vr[k][q] = wr2*vxr - wi2*vxi + cc*vyr;
                            Vi[k][q] = wr2*vxi + wi2*vxr + cc*vyi;
                        }
                        #pragma unroll
                        for (int k = 0; k < 5; ++k) {
                            float xr = Ar[p][k], xi2 = Ai[p][k];
                            float yr = Ar[q][k], yi = Ai[q][k];
                            Ar[p][k] = cc*xr - (wr2*yr - wi2*yi);
                            Ai[p][k] = cc*xi2 - (wr2*yi + wi2*yr);
                            Ar[q][k] = wr2*xr + wi2*xi2 + cc*yr;
                            Ai[q][k] = wr2*xi2 - wi2*xr + cc*yi;
                        }
                    }
                }
            }
        }
        float sv[5], s0 = 0.f;
        #pragma unroll
        for (int k = 0; k < 5; ++k) { sv[k] = sqrtf(fmaxf(Ar[k][k], 0.f)); s0 = fmaxf(s0, sv[k]); }
        float th = fmaxf(thres[b], 0.f) * s0;
        float ratio[5];
        #pragma unroll
        for (int k = 0; k < 5; ++k)
            ratio[k] = sv[k] > 0.f ? fmaxf(sv[k] - th, 0.f) / sv[k] : 0.f;
        #pragma unroll
        for (int a = 0; a < 5; ++a)
            #pragma unroll
            for (int c = 0; c < 5; ++c) {
                float wr = 0.f, wi = 0.f;
                #pragma unroll
                for (int k = 0; k < 5; ++k) {
                    wr += ratio[k] * (Vr[a][k]*Vr[c][k] + Vi[a][k]*Vi[c][k]);
                    wi += ratio[k] * (Vi[a][k]*Vr[c][k] - Vr[a][k]*Vi[c][k]);
                }
                sW[b*50 + (a*5+c)*2]   = wr;
                sW[b*50 + (a*5+c)*2+1] = wi;
            }
    }
    __syncthreads();
    for (int it = tid; it < 245*25; it += 128) {
        int blk = it / 25, e = it % 25;
        int chunk = blk / 49;
        int rem = blk % 49;
        int rx = rem / 7, ry = rem % 7;
        int i0 = rx >> 1, i1 = (rx + 1) >> 1;
        int j0 = ry >> 1, j1 = (ry + 1) >> 1;
        float sr = 0.f, si = 0.f; int cnt = 0;
        for (int i = i0; i <= i1; ++i)
            for (int j = j0; j <= j1; ++j) {
                int b = chunk*16 + i*4 + j;
                sr += sW[b*50 + e*2];
                si += sW[b*50 + e*2 + 1];
                ++cnt;
            }
        float inv = 1.f / (float)cnt;
        gA[blk*50 + e*2]   = sr * inv;
        gA[blk*50 + e*2+1] = si * inv;
    }
}

// ---------------- K4: q_re = Re(Wavg * x5) ; out += q_re*(1-p_w)   (fp32 RMW)
__global__ __launch_bounds__(256) void k_final(
    const float* __restrict__ re, const float* __restrict__ im,
    const float* __restrict__ gA, const float* __restrict__ p_w,
    float* __restrict__ out)
{
    int pix = blockIdx.x * 256 + threadIdx.x;
    int chunk = blockIdx.y;
    int X = pix / NXY, Y = pix % NXY;
    int i_lo = (X - 4) / SXY; if (i_lo < 0) i_lo = 0;
    int i_hi = X / SXY;       if (i_hi > 3) i_hi = 3;
    int j_lo = (Y - 4) / SXY; if (j_lo < 0) j_lo = 0;
    int j_hi = Y / SXY;       if (j_hi > 3) j_hi = 3;
    int rx = i_lo + i_hi, ry = j_lo + j_hi;
    const float* wa = gA + (size_t)(chunk*49 + rx*7 + ry) * 50;
    float Wr[5][5], Wi[5][5];
    #pragma unroll
    for (int a = 0; a < 5; ++a)
        #pragma unroll
        for (int r = 0; r < 5; ++r) {
            Wr[a][r] = wa[(a*5+r)*2];
            Wi[a][r] = wa[(a*5+r)*2+1];
        }
    float xr[5], xi[5];
    #pragma unroll
    for (int r = 0; r < 5; ++r) {
        size_t a = (size_t)(chunk*5+r)*NPIX + pix;
        xr[r] = re[a]; xi[r] = im[a];
    }
    float qwv = 1.f - p_w[0];
    #pragma unroll
    for (int tl = 0; tl < 5; ++tl) {
        float qr = 0.f;
        #pragma unroll
        for (int r = 0; r < 5; ++r)
            qr += Wr[tl][r]*xr[r] - Wi[tl][r]*xi[r];
        size_t idx = (size_t)(chunk*5+tl)*NPIX + pix;
        out[idx] += qr*qwv;
    }
}

extern "C" void kernel_launch(void* const* d_in, const int* in_sizes, int n_in,
                              void* d_out, int out_size, void* d_ws, size_t ws_size,
                              hipStream_t stream)
{
    const float* re    = (const float*)d_in[0];
    const float* im    = (const float*)d_in[1];
    const float* w1r   = (const float*)d_in[2];
    const float* w1i   = (const float*)d_in[3];
    const float* b1r   = (const float*)d_in[4];
    const float* b1i   = (const float*)d_in[5];
    const float* w2r   = (const float*)d_in[6];
    const float* w2i   = (const float*)d_in[7];
    const float* b2r   = (const float*)d_in[8];
    const float* b2i   = (const float*)d_in[9];
    const float* w3r   = (const float*)d_in[10];
    const float* w3i   = (const float*)d_in[11];
    const float* b3r   = (const float*)d_in[12];
    const float* thres = (const float*)d_in[14];
    const float* tau_w = (const float*)d_in[15];
    const float* p_w   = (const float*)d_in[16];
    const int* num_iter= (const int*)d_in[17];

    float* ws = (float*)d_ws;
    unsigned int* wt1h = (unsigned int*)ws;          // 600 uints
    unsigned int* wt2h = wt1h + 600;                 // 864 uints
    float* gP  = (float*)(wt2h + 864);               // 80*GSL*50 = 32000 floats
    float* gA  = gP + 80*GSL*50;                     // 245*50 floats

    float* outf = (float*)d_out;

    k_prep<<<2, 256, 0, stream>>>(w1r, w1i, w2r, w2i, wt1h, wt2h);
    dim3 g1(NXY/TW, NXY/TH, NZ + 1);                 // z==NZ slice = gram blocks
    k_work<<<g1, 256, 0, stream>>>(re, im, wt1h, wt2h,
                                   b1r, b1i, b2r, b2i, w3r, w3i, b3r,
                                   tau_w, p_w, num_iter, outf, gP);
    k_post<<<1, 128, 0, stream>>>(gP, thres, gA);
    dim3 g4(NPIX/256, 5);
    k_final<<<g4, 256, 0, stream>>>(re, im, gA, p_w, outf);
}